// Round 9
// baseline (167.789 us; speedup 1.0000x reference)
//
#include <hip/hip_runtime.h>
#include <stdint.h>

// FC tensor product, f16, MFMA f32_32x32x16_f16.
// R9: 2048 perfectly-uniform single-phase jobs, 1 wave each (64 thr), zero
// barriers. Wave tile = 128 rows x 64 cols (MFMA:af-VALU = 2:1). W streams
// through 4x4KB private LDS slots (counted vmcnt, depth 3); a through 2x2KB
// slots; b-tile lives in 64 VGPRs per phase. K-split partials -> f16 slabs,
// folded by ep_add. Sign/scale folded into the store.

typedef _Float16 f16;
typedef f16 f16x8 __attribute__((ext_vector_type(8)));
typedef float f32x16 __attribute__((ext_vector_type(16)));
typedef int i32x4 __attribute__((ext_vector_type(4)));

#define OFF_W000 0u
#define OFF_W110 2097152u
#define OFF_W011 2621440u
#define OFF_W101 3145728u
#define OFF_W111 3670016u
#define OFF_XS1  3932160u
#define OFF_XS2  4980736u
#define OFF_XV1  6029312u
#define OFF_XV2  7602176u
#define OFF_S0   9175040u        // 6 x 2 x 8192x64 f16
#define OFF_S1   15466496u       // 3 x 3 x 8192x64
#define OFF_S2   20185088u       // 3 x 8192x64
#define WS_ELEMS 21757952u       // f16 elems (~43.5 MB)

#define SC_0E 0.006987712429686843f
#define SC_1O 0.0078125f
#define SC_1E 0.011048543456039806f

// ---------------- pre-kernel: retile to f16 (32x32-MFMA-native) ----------------
// W macro-tile (4KB): [ct2][kk2][half2][col32][e8]; v = vhalf*32+kk*16+half*8+e.
// total threads = 9175040 = 35840 * 256 (exact bounds per section)
__global__ void tile_all_k(const float* __restrict__ w000, const float* __restrict__ w011,
                           const float* __restrict__ w101, const float* __restrict__ w110,
                           const float* __restrict__ w111, const float* __restrict__ x1,
                           const float* __restrict__ x2, f16* __restrict__ ws)
{
  unsigned tid = blockIdx.x*256u + threadIdx.x;
  if (tid < 2097152u) {  // W000t [q=(vh*2+uh)*2+h][t128][tile]
    unsigned e=tid&7u, col=(tid>>3)&31u, hf=(tid>>8)&1u, kk=(tid>>9)&1u,
             ct=(tid>>10)&1u, t=(tid>>11)&127u, q=tid>>18;
    unsigned h=q&1u, uh=(q>>1)&1u, vh=q>>2;
    unsigned u = uh*64u + (t>>1);
    unsigned v = vh*64u + (t&1u)*32u + kk*16u + hf*8u + e;
    unsigned n = h*64u + ct*32u + col;
    ws[OFF_W000+tid] = (f16)w000[u*16384u + v*128u + n];
    return;
  }
  tid -= 2097152u;
  if (tid < 524288u) {   // W110t [h][t128][tile], fold 1/sqrt3
    unsigned e=tid&7u, col=(tid>>3)&31u, hf=(tid>>8)&1u, kk=(tid>>9)&1u,
             ct=(tid>>10)&1u, t=(tid>>11)&127u, h=tid>>18;
    unsigned u = t>>1;
    unsigned v = (t&1u)*32u + kk*16u + hf*8u + e;
    unsigned n = h*64u + ct*32u + col;
    ws[OFF_W110+tid] = (f16)(w110[u*8192u + v*128u + n] * 0.5773502691896258f);
    return;
  }
  tid -= 524288u;
  if (tid < 524288u) {   // W011t [uh][t128][tile]
    unsigned e=tid&7u, col=(tid>>3)&31u, hf=(tid>>8)&1u, kk=(tid>>9)&1u,
             ct=(tid>>10)&1u, t=(tid>>11)&127u, uh=tid>>18;
    unsigned u = uh*64u + (t>>1);
    unsigned v = (t&1u)*32u + kk*16u + hf*8u + e;
    unsigned n = ct*32u + col;
    ws[OFF_W011+tid] = (f16)w011[u*4096u + v*64u + n];
    return;
  }
  tid -= 524288u;
  if (tid < 524288u) {   // W101t [uh][t128][tile]  (u = s2 idx, v = v1 idx)
    unsigned e=tid&7u, col=(tid>>3)&31u, hf=(tid>>8)&1u, kk=(tid>>9)&1u,
             ct=(tid>>10)&1u, t=(tid>>11)&127u, uh=tid>>18;
    unsigned u = uh*64u + (t>>1);
    unsigned v = (t&1u)*32u + kk*16u + hf*8u + e;
    unsigned n = ct*32u + col;
    ws[OFF_W101+tid] = (f16)w101[v*8192u + u*64u + n];
    return;
  }
  tid -= 524288u;
  if (tid < 262144u) {   // W111t [t128][tile]
    unsigned e=tid&7u, col=(tid>>3)&31u, hf=(tid>>8)&1u, kk=(tid>>9)&1u,
             ct=(tid>>10)&1u, t=tid>>11;
    unsigned u = t>>1;
    unsigned v = (t&1u)*32u + kk*16u + hf*8u + e;
    unsigned n = ct*32u + col;
    ws[OFF_W111+tid] = (f16)w111[u*4096u + v*64u + n];
    return;
  }
  tid -= 262144u;
  if (tid < 1048576u) {  // XS1 [o16][r8192][8]
    unsigned e=tid&7u, r=(tid>>3)&8191u, o=tid>>16;
    ws[OFF_XS1+tid] = (f16)x1[r*320u + o*8u + e];
    return;
  }
  tid -= 1048576u;
  if (tid < 1048576u) {  // XS2
    unsigned e=tid&7u, r=(tid>>3)&8191u, o=tid>>16;
    ws[OFF_XS2+tid] = (f16)x2[r*320u + o*8u + e];
    return;
  }
  tid -= 1048576u;
  if (tid < 1572864u) {  // XV1 [i3][o8][r8192][8]
    unsigned e=tid&7u, r=(tid>>3)&8191u, o=(tid>>16)&7u, i=tid>>19;
    ws[OFF_XV1+tid] = (f16)x1[r*320u + 128u + (o*8u+e)*3u + i];
    return;
  }
  tid -= 1572864u;
  {                      // XV2
    unsigned e=tid&7u, r=(tid>>3)&8191u, o=(tid>>16)&7u, i=tid>>19;
    ws[OFF_XV2+tid] = (f16)x2[r*320u + 128u + (o*8u+e)*3u + i];
  }
}

// ---------------- main kernel ----------------
#define GLD16(g,l) __builtin_amdgcn_global_load_lds( \
    (const __attribute__((address_space(1))) unsigned int*)(g), \
    (__attribute__((address_space(3))) unsigned int*)(l), 16, 0, 0)

#define WAITV(n) asm volatile("s_waitcnt vmcnt(" #n ")" ::: "memory")
#define SBAR0 __builtin_amdgcn_sched_barrier(0)

// One phase: 128 K32-macros (64 u x 2 vhalf), wave-private, barrier-free.
// vmcnt FIFO (4/stage, 2/stA): prologue [stA,st0,st1,st2];
// kc==0: WAITV(8) drains stA+st(t); kc 1..13: WAITV(8); kc==14/15: WAITV(10)
// (stA mid-queue); last ss: kc14 WAITV(4), kc15 WAITV(0). Issue stage(t+3)
// into slot (kc+3)&3 and stA(ss+1) at kc==13.
__device__ __forceinline__ void run_phase(
    const f16* __restrict__ Wq, const f16* __restrict__ aPl, int uob,
    const f16* __restrict__ bPl, int ob, int rowb,
    f16* sW, f16* sA, int lane, f32x16 (&acc)[4][2])
{
  const int l31 = lane & 31, hf = lane >> 5;
  constexpr int SS = 8;

  WAITV(0);
  // b-tile (128 rows x 64 v) -> 64 VGPR, u-independent for the whole phase
  f16x8 br[4][2][2];
#pragma unroll
  for (int rt=0; rt<4; ++rt)
#pragma unroll
    for (int vh=0; vh<2; ++vh)
#pragma unroll
      for (int kk=0; kk<2; ++kk)
        br[rt][vh][kk] = *(const f16x8*)(bPl +
            ((unsigned)(ob + vh*4 + kk*2 + hf)*8192u + (unsigned)(rowb + rt*32 + l31))*8u);
#pragma unroll
  for (int rt=0; rt<4; ++rt)
#pragma unroll
    for (int vh=0; vh<2; ++vh)
#pragma unroll
      for (int kk=0; kk<2; ++kk) {   // force completion: vmcnt -> 0 before staging
        i32x4 tmp = __builtin_bit_cast(i32x4, br[rt][vh][kk]);
        asm volatile("" :: "v"(tmp));
      }

  const char* Ws = (const char*)Wq + lane*16;
  auto stage = [&](int t, int slot){
    const char* s = Ws + t*4096;
    char* d = (char*)sW + slot*4096;
    GLD16(s,      d);
    GLD16(s+1024, d+1024);
    GLD16(s+2048, d+2048);
    GLD16(s+3072, d+3072);
  };
  const char* As = (const char*)aPl + (size_t)uob*131072 + (size_t)rowb*16 + lane*16;
  auto stA = [&](int ss2){
    const char* s = As + ss2*131072;
    char* d = (char*)sA + (ss2&1)*2048;
    GLD16(s,      d);
    GLD16(s+1024, d+1024);
  };

  stA(0); stage(0,0); stage(1,1); stage(2,2);

  f16x8 aR[4];
#pragma unroll 1
  for (int ss=0; ss<SS; ++ss) {
#pragma unroll
    for (int kc=0; kc<16; ++kc) {
      if (kc==14)      { if (ss==SS-1) { WAITV(4); } else { WAITV(10); } }
      else if (kc==15) { if (ss==SS-1) { WAITV(0); } else { WAITV(10); } }
      else             { WAITV(8); }
      SBAR0;
      if (kc==13 && ss<SS-1) stA(ss+1);
      if (kc<13 || ss<SS-1) stage(ss*16+kc+3, (kc+3)&3);
      if (kc==0) {
#pragma unroll
        for (int rt=0; rt<4; ++rt)
          aR[rt] = *(const f16x8*)(sA + (ss&1)*1024 + (rt*32+l31)*8);
      }
      const f16* Wl = sW + (kc&3)*2048;
      __builtin_amdgcn_s_setprio(1);
#pragma unroll
      for (int kk=0; kk<2; ++kk) {
        f16x8 af[4];
#pragma unroll
        for (int rt=0; rt<4; ++rt) {
          f16 av = aR[rt][kc>>1];            // u-elem, compile-time
          af[rt] = av * br[rt][kc&1][kk];    // vhalf = kc&1, compile-time
        }
#pragma unroll
        for (int ct=0; ct<2; ++ct) {
          f16x8 bw = *(const f16x8*)(Wl + (ct*2+kk)*512 + hf*256 + l31*8);
#pragma unroll
          for (int rt=0; rt<4; ++rt)
            acc[rt][ct] = __builtin_amdgcn_mfma_f32_32x32x16_f16(af[rt], bw, acc[rt][ct], 0,0,0);
        }
      }
      __builtin_amdgcn_s_setprio(0);
    }
  }
}

__global__ __launch_bounds__(64, 2)
void tp_main(f16* __restrict__ ws, float* __restrict__ out)
{
  __shared__ f16 smem[10240];      // 20KB: sW 4x4KB | sA 2x2KB
  f16* sW = smem;
  f16* sA = smem + 8192;
  const int lane = threadIdx.x & 63;
  const int l31 = lane & 31, hf = lane >> 5;

  f32x16 acc[4][2];
#pragma unroll
  for (int a=0; a<4; ++a)
#pragma unroll
    for (int b=0; b<2; ++b)
#pragma unroll
      for (int r=0; r<16; ++r) acc[a][b][r] = 0.f;

  // XCD grouping: jobs sharing a W stream land on the same XCD's L2
  const int bid = blockIdx.x;
  const int jid = (bid&7)*256 + (bid>>3);

  const f16 *Wq, *aPl, *bPl;
  int uob=0, ob=0, rowb, cbase=0, cmul=1;
  unsigned sbase=0; bool direct; float sc;

  if (jid < 512) {               // J0a: w000, quadrant q=(vh,uh,h)
    int rt = jid & 63, q = jid >> 6;
    int h = q&1, uh = (q>>1)&1, vh = q>>2;
    Wq  = ws + OFF_W000 + (unsigned)q*262144u;
    aPl = ws + OFF_XS1;  uob = uh*8;
    bPl = ws + OFF_XS2;  ob  = vh*8;
    rowb = rt*128; sc = SC_0E;
    direct = (vh==0 && uh==0);
    cbase = h*64; cmul = 1;
    sbase = OFF_S0 + (unsigned)(((vh*2+uh-1)*2 + h))*524288u;
  } else if (jid < 896) {        // J0b: w110' comp i, n-half h -> slab
    int s = jid-512, rt = s&63, g = s>>6, i = g%3, h = g/3;
    Wq  = ws + OFF_W110 + (unsigned)h*262144u;
    aPl = ws + OFF_XV1 + (unsigned)i*524288u;
    bPl = ws + OFF_XV2 + (unsigned)i*524288u;
    rowb = rt*128; sc = SC_0E; direct = false;
    sbase = OFF_S0 + (unsigned)((3+i)*2 + h)*524288u;
  } else if (jid < 1280) {       // J1o-a: w011 (a=s1, b=v2_i), u-half uh
    int s = jid-896, rt = s&63, g = s>>6, i = g%3, uh = g/3;
    Wq  = ws + OFF_W011 + (unsigned)uh*262144u;
    aPl = ws + OFF_XS1;  uob = uh*8;
    bPl = ws + OFF_XV2 + (unsigned)i*524288u;
    rowb = rt*128; sc = SC_1O;
    direct = (uh==0); cbase = 128+i; cmul = 3;
    sbase = OFF_S1 + (unsigned)i*524288u;
  } else if (jid < 1664) {       // J1o-b: w101 (a=s2, b=v1_i) -> slab
    int s = jid-1280, rt = s&63, g = s>>6, i = g%3, uh = g/3;
    Wq  = ws + OFF_W101 + (unsigned)uh*262144u;
    aPl = ws + OFF_XS2;  uob = uh*8;
    bPl = ws + OFF_XV1 + (unsigned)i*524288u;
    rowb = rt*128; sc = SC_1O; direct = false;
    sbase = OFF_S1 + (unsigned)((1+uh)*3 + i)*524288u;
  } else {                       // J1e: w111 cross comp kk, sign sg
    int s = jid-1664, rt = s&63, g = s>>6, kk = g%3, sg = g/3;
    int i = kk+1; if (i>2) i-=3;
    int j = kk+2; if (j>2) j-=3;
    Wq = ws + OFF_W111;
    if (sg==0) { aPl = ws + OFF_XV1 + (unsigned)i*524288u; bPl = ws + OFF_XV2 + (unsigned)j*524288u; }
    else       { aPl = ws + OFF_XV1 + (unsigned)j*524288u; bPl = ws + OFF_XV2 + (unsigned)i*524288u; }
    rowb = rt*128; sc = (sg==0) ? SC_1E : -SC_1E;   // sign folded into scale
    direct = (sg==0); cbase = 320+kk; cmul = 3;
    sbase = OFF_S2 + (unsigned)kk*524288u;
  }

  run_phase(Wq, aPl, uob, bPl, ob, rowb, sW, sA, lane, acc);

  // store: C layout (32x32): col = l31, row = (reg&3)+8*(reg>>2)+4*(lane>>5)
  if (direct) {
#pragma unroll
    for (int rt=0; rt<4; ++rt)
#pragma unroll
      for (int ct=0; ct<2; ++ct)
#pragma unroll
        for (int rg=0; rg<16; ++rg) {
          int row = (rg&3) + 8*(rg>>2) + 4*hf;
          out[(unsigned)(rowb + rt*32 + row)*512u + (unsigned)(cbase + cmul*(ct*32 + l31))]
              = sc * acc[rt][ct][rg];
        }
  } else {
#pragma unroll
    for (int rt=0; rt<4; ++rt)
#pragma unroll
      for (int ct=0; ct<2; ++ct)
#pragma unroll
        for (int rg=0; rg<16; ++rg) {
          int row = (rg&3) + 8*(rg>>2) + 4*hf;
          ws[sbase + (unsigned)(rowb + rt*32 + row)*64u + (unsigned)(ct*32 + l31)]
              = (f16)(sc * acc[rt][ct][rg]);
        }
  }
}

// ---------------- epilogue: fold f16 slabs into out ----------------
__global__ void ep_add(const f16* __restrict__ ws, float* __restrict__ out)
{
  unsigned tid = blockIdx.x*256u + threadIdx.x;   // 4194304 exactly
  unsigned r = tid >> 9, c = tid & 511u;
  float s = 0.f;
  if (c < 128u) {
    unsigned h = c>>6, cc = c&63u;
#pragma unroll
    for (int j=0; j<6; ++j)
      s += (float)ws[OFF_S0 + ((unsigned)(j*2)+h)*524288u + r*64u + cc];
  } else if (c < 320u) {
    unsigned t = c-128u, n = (t*21846u)>>16, i = t - n*3u;
#pragma unroll
    for (int j=0; j<3; ++j)
      s += (float)ws[OFF_S1 + ((unsigned)j*3u+i)*524288u + r*64u + n];
  } else {
    unsigned t = c-320u, n = (t*21846u)>>16, kk = t - n*3u;
    s = (float)ws[OFF_S2 + kk*524288u + r*64u + n];
  }
  out[tid] += s;
}

extern "C" void kernel_launch(void* const* d_in, const int* in_sizes, int n_in,
                              void* d_out, int out_size, void* d_ws, size_t ws_size,
                              hipStream_t stream)
{
  const float* x1   = (const float*)d_in[0];
  const float* x2   = (const float*)d_in[1];
  const float* w000 = (const float*)d_in[2];
  const float* w011 = (const float*)d_in[3];
  const float* w101 = (const float*)d_in[4];
  const float* w110 = (const float*)d_in[5];
  const float* w111 = (const float*)d_in[6];
  float* out = (float*)d_out;
  f16* ws   = (f16*)d_ws;

  if (ws_size < (size_t)WS_ELEMS * 2) return;   // ~43.5 MB scratch

  tile_all_k<<<35840, 256, 0, stream>>>(w000, w011, w101, w110, w111, x1, x2, ws);
  tp_main<<<2048, 64, 0, stream>>>(ws, out);
  ep_add<<<16384, 256, 0, stream>>>(ws, out);
}